// Round 11
// baseline (222.141 us; speedup 1.0000x reference)
//
#include <hip/hip_runtime.h>

// Problem: B=2, H=4, S=4096, D=64.  q,k,v fp32; mask int32.
// Outputs (fp32, concatenated): out [2,4,4096,64] then attn [2,4,4096,4096].
#define SDIM 4096
#define DDIM 64
#define HDIM 4
#define OUTN (2 * HDIM * SDIM * DDIM)   // 2,097,152 floats of `out` before `attn`

typedef short short8 __attribute__((ext_vector_type(8)));  // 8 x bf16 (4 VGPRs)
typedef short bh4    __attribute__((ext_vector_type(4)));  // 4 x bf16 (2 VGPRs)
typedef float f32x4  __attribute__((ext_vector_type(4)));

__device__ inline short f2bf(float f) {
    // round-to-nearest-even fp32 -> bf16
    unsigned u = __builtin_bit_cast(unsigned, f);
    u = (u + 0x7fffu + ((u >> 16) & 1u)) >> 16;
    return (short)u;
}
__device__ inline float bf2f(short s) {
    unsigned u = ((unsigned)(unsigned short)s) << 16;
    return __builtin_bit_cast(float, u);
}

// K/V LDS tiles are [64][64] shorts (128 B rows), XOR-swizzled: the 16-B
// chunk index (byte bits 4-6) is XORed with (row&7).  Keeps ds_read_b128 at
// the 8-cycle minimum (8 lanes / 4-bank group) with zero padding.
__device__ inline short* ldsp(short* base, int row, int colshort) {
    int byte = (row << 7) + (colshort << 1);
    byte ^= (row & 7) << 4;
    return (short*)((char*)base + byte);
}

// P accumulation tile is [64][256] shorts (512 B rows), same XOR scheme.
__device__ inline short* ldsp2(short* base, int row, int colshort) {
    int byte = (row << 9) + (colshort << 1);
    byte ^= (row & 7) << 4;
    return (short*)((char*)base + byte);
}

// async 16-B global -> LDS DMA (linear LDS dest; source is pre-swizzled)
__device__ inline void g2l16(const short* g, short* l) {
    __builtin_amdgcn_global_load_lds(
        (const __attribute__((address_space(1))) unsigned int*)g,
        (__attribute__((address_space(3))) unsigned int*)l, 16, 0, 0);
}

// ---------------------------------------------------------------------------
// Pre-pass 1: bit-pack mask (1,S,S) int32 -> 1 bit per element (2 MB in ws).
__global__ void pack_mask(const int* __restrict__ mask,
                          unsigned long long* __restrict__ bits) {
    int gid = blockIdx.x * 256 + threadIdx.x;
    int v = (mask[gid] != 0);
    unsigned long long bal = __ballot(v);
    if ((threadIdx.x & 63) == 0) bits[gid >> 6] = bal;
}

// ---------------------------------------------------------------------------
// Pre-pass 2: fp32 -> bf16 copy (for Q and K). 8 elems/thread.
__global__ void cvt_bf16(const float* __restrict__ src, short* __restrict__ dst) {
    int gid = blockIdx.x * 256 + threadIdx.x;
    const float* p = src + (size_t)gid * 8;
    f32x4 a = *(const f32x4*)p;
    f32x4 b = *(const f32x4*)(p + 4);
    short8 o;
#pragma unroll
    for (int j = 0; j < 4; ++j) { o[j] = f2bf(a[j]); o[j + 4] = f2bf(b[j]); }
    *(short8*)(dst + (size_t)gid * 8) = o;
}

// ---------------------------------------------------------------------------
// Pre-pass 3: VT[b][h][d][t] = bf16(V[b][h][t][d])  (4 MB in ws).
__global__ void transpose_v(const float* __restrict__ v, short* __restrict__ vt) {
    int gid = blockIdx.x * 256 + threadIdx.x;          // 8*64*512 = 262144 threads
    int t8 = gid & (SDIM / 8 - 1);                     // 0..511
    int d  = (gid >> 9) & (DDIM - 1);
    int bh = gid >> 15;                                // 0..7
    short8 o;
#pragma unroll
    for (int j = 0; j < 8; ++j)
        o[j] = f2bf(v[((size_t)bh * SDIM + t8 * 8 + j) * DDIM + d]);
    *(short8*)(vt + ((size_t)bh * DDIM + d) * SDIM + t8 * 8) = o;
}

// ---------------------------------------------------------------------------
// Fused kernel: block = (head h, 64 q-rows, BOTH batches, half the t range).
// XCD-AWARE BLOCK SWIZZLE (T1): linear block id is transposed (orig%8)*64 +
// orig/8 so that, under round-robin dispatch, XCD i runs exactly the 64
// s0-blocks of (h,tz)-combo i.  All 64 share the same 1 MB K/V working set
// -> staged reads hit the XCD's 4 MB L2 (R10: -21 us confirmed).
// Per 64-wide t tile: S_b = Q_b K_b^T (MFMA) -> p0 = sigmoid((S0-S1)/8)
// (0.5 where masked) -> P0 into a 4-tile LDS accumulator (bf16; P1 = 1-P0
// recomputed in-register) -> O_b += P_b V_b (MFMA).  Every 4th tile: flush
// attn (1 KB contiguous fp32 per row) with PLAIN stores -- post-swizzle A/B
// vs nontemporal: NT no-allocate bypasses L2 write-combining (~3.7 TB/s
// observed); plain stores take the L2 write-back full-line path (the
// 6.6 TB/s fill path), and the K/V read set is now L2-stable so allocation
// no longer thrashes it.
// Partial O to ws; combined by `combine`.  LDS = 64 KB -> 2 blocks/CU.
__global__ __launch_bounds__(256, 2)
void attn_fused(const short* __restrict__ qg, const short* __restrict__ kg,
                const short* __restrict__ vtg,
                const unsigned long long* __restrict__ mbits,
                float* __restrict__ attng, float* __restrict__ opart) {
    __shared__ short Ks [2][64 * 64];       // K tile, rows = t (swizzled)
    __shared__ short VTs[2][64 * 64];       // V^T tile, rows = d (swizzled)
    __shared__ short Ps [64 * 256];         // P0 x 4 t-tiles, rows = m (swizzled)

    // XCD swizzle: orig -> swz (bijective 8x64 transpose over the 512 blocks)
    const int orig = blockIdx.x + (blockIdx.y << 6) + (blockIdx.z << 8);
    const int swz  = (orig & 7) * 64 + (orig >> 3);
    const int s0   = (swz & 63) << 6;       // q-row block
    const int cmb  = swz >> 6;              // (h,tz) combo 0..7
    const int h    = cmb & 3;
    const int tz   = cmb >> 2;              // t-half: [tz*2048, tz*2048+2048)

    const int tid = threadIdx.x;
    const int wv  = tid >> 6;               // wave 0..3, owns q-rows 16*wv..+15
    const int ln  = tid & 63;
    const int l   = ln & 15;
    const int qd  = ln >> 4;                // quad

    // Q A-fragments (A[m=lane&15][k=quad*8+j]), kept in registers.
    short8 qf[2][2];
#pragma unroll
    for (int b = 0; b < 2; ++b) {
        const size_t rb = ((size_t)(b * HDIM + h) * SDIM + (s0 + wv * 16 + l)) * DDIM;
#pragma unroll
        for (int kc = 0; kc < 2; ++kc)
            qf[b][kc] = *(const short8*)(qg + rb + kc * 32 + qd * 8);
    }

    f32x4 oacc[2][4];
#pragma unroll
    for (int b = 0; b < 2; ++b)
#pragma unroll
        for (int nd = 0; nd < 4; ++nd)
            oacc[b][nd] = (f32x4){0.f, 0.f, 0.f, 0.f};

    // staging geometry: lane ln covers dest row (p*32 + wv*8 + ln>>3),
    // chunk (ln&7); source chunk is inverse-swizzled so swizzled reads match.
    const int ln8 = ln >> 3;                 // dest row within 8-row group
    const int sc_ = (ln & 7) ^ ln8;          // pre-swizzled source 16-B chunk
    const int mrow0 = s0 + wv * 16 + qd * 4; // this quad's first C row

    const int tbeg = tz * (SDIM / 2);
    for (int t0 = tbeg; t0 < tbeg + SDIM / 2; t0 += 64) {
        __syncthreads();   // all waves done reading Ks/VTs of previous tile
#pragma unroll
        for (int b = 0; b < 2; ++b) {
            const short* kb = kg  + ((size_t)(b * HDIM + h) * SDIM + t0) * DDIM;
            const short* vb = vtg + ((size_t)(b * HDIM + h) * DDIM) * SDIM + t0;
#pragma unroll
            for (int p = 0; p < 2; ++p) {
                int rr = p * 32 + wv * 8 + ln8;
                g2l16(kb + (size_t)rr * DDIM + sc_ * 8, &Ks [b][p * 2048 + wv * 512]);
                g2l16(vb + (size_t)rr * SDIM + sc_ * 8, &VTs[b][p * 2048 + wv * 512]);
            }
        }
        // mask bits: one u64 per C row covers the 64 t of this tile
        // (independent of LDS -> issued under the staging DMA latency)
        unsigned long long mw[4];
#pragma unroll
        for (int rg = 0; rg < 4; ++rg)
            mw[rg] = mbits[(size_t)(mrow0 + rg) * (SDIM / 64) + (t0 >> 6)];
        __syncthreads();   // vmcnt(0) drain -> staged tiles visible

        const int g = (t0 >> 6) & 3;        // tile index within the 4-tile group

        // QK^T: B[k][n] = K[n][k] -> read K rows like A-frags
        f32x4 sc[2][4];
#pragma unroll
        for (int b = 0; b < 2; ++b)
#pragma unroll
            for (int nt = 0; nt < 4; ++nt) {
                f32x4 acc = (f32x4){0.f, 0.f, 0.f, 0.f};
#pragma unroll
                for (int kc = 0; kc < 2; ++kc) {
                    short8 bf = *(const short8*)ldsp(&Ks[b][0], nt * 16 + l, kc * 32 + qd * 8);
                    acc = __builtin_amdgcn_mfma_f32_16x16x32_bf16(qf[b][kc], bf, acc, 0, 0, 0);
                }
                sc[b][nt] = acc;
            }

        // batch-pair sigmoid; P0 -> Ps slot g (bf16, wave-local rows;
        // same-wave DS ordering covers the later same-wave reads)
#pragma unroll
        for (int nt = 0; nt < 4; ++nt)
#pragma unroll
            for (int rg = 0; rg < 4; ++rg) {
                float dd = (sc[0][nt][rg] - sc[1][nt][rg]) * 0.125f;
                bool msk = (mw[rg] >> (nt * 16 + l)) & 1ull;
                float p0 = msk ? 0.5f : __builtin_amdgcn_rcpf(1.f + __expf(-dd));
                int row = wv * 16 + qd * 4 + rg;
                *ldsp2(&Ps[0], row, g * 64 + nt * 16 + l) = f2bf(p0);
            }

        // PV: A from Ps slot g (own 16-row strip; b=1 frag = 1 - b=0 frag),
        // B from VTs (rows = d)
#pragma unroll
        for (int kc = 0; kc < 2; ++kc) {
            short8 af0 = *(const short8*)ldsp2(&Ps[0], wv * 16 + l, g * 64 + kc * 32 + qd * 8);
            short8 af1;
#pragma unroll
            for (int j = 0; j < 8; ++j) af1[j] = f2bf(1.f - bf2f(af0[j]));
#pragma unroll
            for (int nd = 0; nd < 4; ++nd) {
                short8 bf0 = *(const short8*)ldsp(&VTs[0][0], nd * 16 + l, kc * 32 + qd * 8);
                oacc[0][nd] = __builtin_amdgcn_mfma_f32_16x16x32_bf16(af0, bf0, oacc[0][nd], 0, 0, 0);
                short8 bf1 = *(const short8*)ldsp(&VTs[1][0], nd * 16 + l, kc * 32 + qd * 8);
                oacc[1][nd] = __builtin_amdgcn_mfma_f32_16x16x32_bf16(af1, bf1, oacc[1][nd], 0, 0, 0);
            }
        }

        // FLUSH every 4th tile: per 4-row group, 4 consecutive store
        // instructions cover 1 KB CONTIGUOUS fp32 per row (t-inner order).
        // PLAIN (cached) stores -- the single A/B variable this round.
        if (g == 3) {
            int rr2 = ln >> 4;               // row within 4-row group
            int c2  = ln & 15;               // 16-B chunk within a 256-B segment
            int tg0 = t0 & ~255;             // first t of this 4-tile group
#pragma unroll
            for (int b = 0; b < 2; ++b) {
                size_t ab = ((size_t)(b * HDIM + h) * SDIM + s0) * (size_t)SDIM + tg0;
#pragma unroll
                for (int sub = 0; sub < 4; ++sub) {
                    int row = wv * 16 + sub * 4 + rr2;
                    float* dst = attng + ab + (size_t)row * SDIM;
#pragma unroll
                    for (int tch = 0; tch < 4; ++tch) {
                        bh4 pv = *(const bh4*)ldsp2(&Ps[0], row, tch * 64 + c2 * 4);
                        f32x4 o;
#pragma unroll
                        for (int j = 0; j < 4; ++j) {
                            float v = bf2f(pv[j]);
                            o[j] = b ? 1.f - v : v;
                        }
                        *(f32x4*)(dst + tch * 64 + c2 * 4) = o;
                    }
                }
            }
        }
    }

    // epilogue: partial O (C-layout: col=lane&15, row=quad*4+reg) -> ws
#pragma unroll
    for (int b = 0; b < 2; ++b)
#pragma unroll
        for (int nd = 0; nd < 4; ++nd)
#pragma unroll
            for (int rg = 0; rg < 4; ++rg) {
                int srow = s0 + wv * 16 + qd * 4 + rg;
                opart[(size_t)tz * OUTN +
                      ((size_t)(b * HDIM + h) * SDIM + srow) * DDIM + nd * 16 + l] =
                    oacc[b][nd][rg];
            }
}

// ---------------------------------------------------------------------------
// Sum the two t-half partials into out.
__global__ void combine(const float* __restrict__ opart, float* __restrict__ outg) {
    int gid = blockIdx.x * 256 + threadIdx.x;           // OUTN/4 threads
    f32x4 a = *(const f32x4*)(opart + (size_t)gid * 4);
    f32x4 b = *(const f32x4*)(opart + (size_t)OUTN + (size_t)gid * 4);
    *(f32x4*)(outg + (size_t)gid * 4) = a + b;
}

// ---------------------------------------------------------------------------
extern "C" void kernel_launch(void* const* d_in, const int* in_sizes, int n_in,
                              void* d_out, int out_size, void* d_ws, size_t ws_size,
                              hipStream_t stream) {
    (void)in_sizes; (void)n_in; (void)out_size; (void)ws_size;
    const float* qg  = (const float*)d_in[0];
    const float* kg  = (const float*)d_in[1];
    const float* vg  = (const float*)d_in[2];
    const int*   msk = (const int*)d_in[3];

    float* outg  = (float*)d_out;
    float* attng = outg + (size_t)OUTN;

    char* ws = (char*)d_ws;
    unsigned long long* bits = (unsigned long long*)ws;            // 2 MB
    short* qb = (short*)(ws + (size_t) 2 * 1024 * 1024);           // 4 MB
    short* kb = (short*)(ws + (size_t) 6 * 1024 * 1024);           // 4 MB
    short* vt = (short*)(ws + (size_t)10 * 1024 * 1024);           // 4 MB
    float* op = (float*)(ws + (size_t)14 * 1024 * 1024);           // 16.8 MB

    pack_mask  <<<dim3(SDIM * SDIM / 256), dim3(256), 0, stream>>>(msk, bits);
    cvt_bf16   <<<dim3(OUTN / (8 * 256)), dim3(256), 0, stream>>>(qg, qb);
    cvt_bf16   <<<dim3(OUTN / (8 * 256)), dim3(256), 0, stream>>>(kg, kb);
    transpose_v<<<dim3(OUTN / (8 * 256)), dim3(256), 0, stream>>>(vg, vt);
    attn_fused <<<dim3(SDIM / 64, HDIM, 2), dim3(256), 0, stream>>>(qb, kb, vt, bits, attng, op);
    combine    <<<dim3(OUTN / (4 * 256)), dim3(256), 0, stream>>>(op, outg);
}

// Round 12
// 197.756 us; speedup vs baseline: 1.1233x; 1.1233x over previous
//
#include <hip/hip_runtime.h>

// Problem: B=2, H=4, S=4096, D=64.  q,k,v fp32; mask int32.
// Outputs (fp32, concatenated): out [2,4,4096,64] then attn [2,4,4096,4096].
#define SDIM 4096
#define DDIM 64
#define HDIM 4
#define OUTN (2 * HDIM * SDIM * DDIM)   // 2,097,152 floats of `out` before `attn`

typedef short short8 __attribute__((ext_vector_type(8)));  // 8 x bf16 (4 VGPRs)
typedef short bh4    __attribute__((ext_vector_type(4)));  // 4 x bf16 (2 VGPRs)
typedef float f32x4  __attribute__((ext_vector_type(4)));

__device__ inline short f2bf(float f) {
    // round-to-nearest-even fp32 -> bf16
    unsigned u = __builtin_bit_cast(unsigned, f);
    u = (u + 0x7fffu + ((u >> 16) & 1u)) >> 16;
    return (short)u;
}
__device__ inline float bf2f(short s) {
    unsigned u = ((unsigned)(unsigned short)s) << 16;
    return __builtin_bit_cast(float, u);
}

// K/V LDS tiles are [64][64] shorts (128 B rows), XOR-swizzled: the 16-B
// chunk index (byte bits 4-6) is XORed with (row&7).  Keeps ds_read_b128 at
// the 8-cycle minimum (8 lanes / 4-bank group) with zero padding.
__device__ inline short* ldsp(short* base, int row, int colshort) {
    int byte = (row << 7) + (colshort << 1);
    byte ^= (row & 7) << 4;
    return (short*)((char*)base + byte);
}

// P accumulation tile is [64][256] shorts (512 B rows), same XOR scheme.
__device__ inline short* ldsp2(short* base, int row, int colshort) {
    int byte = (row << 9) + (colshort << 1);
    byte ^= (row & 7) << 4;
    return (short*)((char*)base + byte);
}

// async 16-B global -> LDS DMA (linear LDS dest; source is pre-swizzled)
__device__ inline void g2l16(const short* g, short* l) {
    __builtin_amdgcn_global_load_lds(
        (const __attribute__((address_space(1))) unsigned int*)g,
        (__attribute__((address_space(3))) unsigned int*)l, 16, 0, 0);
}

// ---------------------------------------------------------------------------
// Pre-pass 1: bit-pack mask (1,S,S) int32 -> 1 bit per element (2 MB in ws).
__global__ void pack_mask(const int* __restrict__ mask,
                          unsigned long long* __restrict__ bits) {
    int gid = blockIdx.x * 256 + threadIdx.x;
    int v = (mask[gid] != 0);
    unsigned long long bal = __ballot(v);
    if ((threadIdx.x & 63) == 0) bits[gid >> 6] = bal;
}

// ---------------------------------------------------------------------------
// Pre-pass 2: fp32 -> bf16 copy (for Q and K). 8 elems/thread.
__global__ void cvt_bf16(const float* __restrict__ src, short* __restrict__ dst) {
    int gid = blockIdx.x * 256 + threadIdx.x;
    const float* p = src + (size_t)gid * 8;
    f32x4 a = *(const f32x4*)p;
    f32x4 b = *(const f32x4*)(p + 4);
    short8 o;
#pragma unroll
    for (int j = 0; j < 4; ++j) { o[j] = f2bf(a[j]); o[j + 4] = f2bf(b[j]); }
    *(short8*)(dst + (size_t)gid * 8) = o;
}

// ---------------------------------------------------------------------------
// Pre-pass 3: VT[b][h][d][t] = bf16(V[b][h][t][d])  (4 MB in ws).
__global__ void transpose_v(const float* __restrict__ v, short* __restrict__ vt) {
    int gid = blockIdx.x * 256 + threadIdx.x;          // 8*64*512 = 262144 threads
    int t8 = gid & (SDIM / 8 - 1);                     // 0..511
    int d  = (gid >> 9) & (DDIM - 1);
    int bh = gid >> 15;                                // 0..7
    short8 o;
#pragma unroll
    for (int j = 0; j < 8; ++j)
        o[j] = f2bf(v[((size_t)bh * SDIM + t8 * 8 + j) * DDIM + d]);
    *(short8*)(vt + ((size_t)bh * DDIM + d) * SDIM + t8 * 8) = o;
}

// ---------------------------------------------------------------------------
// Fused kernel: block = (head h, 64 q-rows, BOTH batches, half the t range).
// XCD-AWARE BLOCK SWIZZLE (T1, R10: -21 us): XCD i runs the 64 s0-blocks of
// (h,tz)-combo i -> staged K/V reads hit the XCD's 4 MB L2.
// Per 64-wide t tile: S_b = Q_b K_b^T (MFMA) -> p0 = sigmoid((S0-S1)/8)
// (0.5 where masked) -> P0 into a 4-SLOT LDS RING (bf16; P1 = 1-P0
// recomputed in-register) -> O_b += P_b V_b (MFMA).
// RING FLUSH (this round's change): the attn flush of slot g (tile t0-256)
// is issued right AFTER the staging barrier, so its NT stores drain under
// the QK+softmax+PV compute phase instead of being exposed at the next
// barrier's vmcnt(0).  Old structure flushed 128 KB right BEFORE a barrier
// every 4th iteration -> ~50% write duty cycle, ~3.5 TB/s effective.
// Same-wave LDS ordering makes the read(slot g)-before-overwrite safe;
// all Ps rows are wave-local.  Last 4 slots flush in the epilogue.
// Partial O to ws; combined by `combine`.  LDS = 64 KB -> 2 blocks/CU.
__global__ __launch_bounds__(256, 2)
void attn_fused(const short* __restrict__ qg, const short* __restrict__ kg,
                const short* __restrict__ vtg,
                const unsigned long long* __restrict__ mbits,
                float* __restrict__ attng, float* __restrict__ opart) {
    __shared__ short Ks [2][64 * 64];       // K tile, rows = t (swizzled)
    __shared__ short VTs[2][64 * 64];       // V^T tile, rows = d (swizzled)
    __shared__ short Ps [64 * 256];         // P0 ring x 4 slots, rows = m

    // XCD swizzle: orig -> swz (bijective 8x64 transpose over the 512 blocks)
    const int orig = blockIdx.x + (blockIdx.y << 6) + (blockIdx.z << 8);
    const int swz  = (orig & 7) * 64 + (orig >> 3);
    const int s0   = (swz & 63) << 6;       // q-row block
    const int cmb  = swz >> 6;              // (h,tz) combo 0..7
    const int h    = cmb & 3;
    const int tz   = cmb >> 2;              // t-half: [tz*2048, tz*2048+2048)

    const int tid = threadIdx.x;
    const int wv  = tid >> 6;               // wave 0..3, owns q-rows 16*wv..+15
    const int ln  = tid & 63;
    const int l   = ln & 15;
    const int qd  = ln >> 4;                // quad

    // Q A-fragments (A[m=lane&15][k=quad*8+j]), kept in registers.
    short8 qf[2][2];
#pragma unroll
    for (int b = 0; b < 2; ++b) {
        const size_t rb = ((size_t)(b * HDIM + h) * SDIM + (s0 + wv * 16 + l)) * DDIM;
#pragma unroll
        for (int kc = 0; kc < 2; ++kc)
            qf[b][kc] = *(const short8*)(qg + rb + kc * 32 + qd * 8);
    }

    f32x4 oacc[2][4];
#pragma unroll
    for (int b = 0; b < 2; ++b)
#pragma unroll
        for (int nd = 0; nd < 4; ++nd)
            oacc[b][nd] = (f32x4){0.f, 0.f, 0.f, 0.f};

    // staging geometry: lane ln covers dest row (p*32 + wv*8 + ln>>3),
    // chunk (ln&7); source chunk is inverse-swizzled so swizzled reads match.
    const int ln8 = ln >> 3;                 // dest row within 8-row group
    const int sc_ = (ln & 7) ^ ln8;          // pre-swizzled source 16-B chunk
    const int mrow0 = s0 + wv * 16 + qd * 4; // this quad's first C row

    // flush one 64-t tile (slot `slot`, global t-origin tg) with NT stores:
    // per 4-row group, dense 256-B row segments (16 lanes x 16 B per row).
    const int rr2 = ln >> 4;                 // row within 4-row group
    const int c2  = ln & 15;                 // 16-B chunk within the 256-B row
    auto FLUSH = [&](int slot, int tg) {
#pragma unroll
        for (int b = 0; b < 2; ++b) {
            size_t ab = ((size_t)(b * HDIM + h) * SDIM + s0) * (size_t)SDIM + tg;
#pragma unroll
            for (int sub = 0; sub < 4; ++sub) {
                int row = wv * 16 + sub * 4 + rr2;
                bh4 pv = *(const bh4*)ldsp2(&Ps[0], row, slot * 64 + c2 * 4);
                f32x4 o;
#pragma unroll
                for (int j = 0; j < 4; ++j) {
                    float v = bf2f(pv[j]);
                    o[j] = b ? 1.f - v : v;
                }
                __builtin_nontemporal_store(
                    o, (f32x4*)(attng + ab + (size_t)row * SDIM + c2 * 4));
            }
        }
    };

    const int tbeg = tz * (SDIM / 2);
    const int tend = tbeg + SDIM / 2;
    for (int t0 = tbeg; t0 < tend; t0 += 64) {
        __syncthreads();   // waves done with prev Ks/VTs; drains the flush
                           // stores issued one full compute phase ago (cheap)
#pragma unroll
        for (int b = 0; b < 2; ++b) {
            const short* kb = kg  + ((size_t)(b * HDIM + h) * SDIM + t0) * DDIM;
            const short* vb = vtg + ((size_t)(b * HDIM + h) * DDIM) * SDIM + t0;
#pragma unroll
            for (int p = 0; p < 2; ++p) {
                int rr = p * 32 + wv * 8 + ln8;
                g2l16(kb + (size_t)rr * DDIM + sc_ * 8, &Ks [b][p * 2048 + wv * 512]);
                g2l16(vb + (size_t)rr * SDIM + sc_ * 8, &VTs[b][p * 2048 + wv * 512]);
            }
        }
        // mask bits: one u64 per C row covers the 64 t of this tile
        // (independent of LDS -> issued under the staging DMA latency)
        unsigned long long mw[4];
#pragma unroll
        for (int rg = 0; rg < 4; ++rg)
            mw[rg] = mbits[(size_t)(mrow0 + rg) * (SDIM / 64) + (t0 >> 6)];
        __syncthreads();   // staged tiles visible (K/V are L2-hits now)

        const int g = (t0 >> 6) & 3;        // ring slot for this tile

        // RING FLUSH: slot g still holds tile t0-256; write it out NOW so
        // the stores drain under the compute below, then overwrite the slot.
        if (t0 - 256 >= tbeg) FLUSH(g, t0 - 256);

        // QK^T: B[k][n] = K[n][k] -> read K rows like A-frags
        f32x4 sc[2][4];
#pragma unroll
        for (int b = 0; b < 2; ++b)
#pragma unroll
            for (int nt = 0; nt < 4; ++nt) {
                f32x4 acc = (f32x4){0.f, 0.f, 0.f, 0.f};
#pragma unroll
                for (int kc = 0; kc < 2; ++kc) {
                    short8 bf = *(const short8*)ldsp(&Ks[b][0], nt * 16 + l, kc * 32 + qd * 8);
                    acc = __builtin_amdgcn_mfma_f32_16x16x32_bf16(qf[b][kc], bf, acc, 0, 0, 0);
                }
                sc[b][nt] = acc;
            }

        // batch-pair sigmoid; P0 -> Ps slot g (bf16, wave-local rows;
        // same-wave LDS ordering: these writes follow the FLUSH reads)
#pragma unroll
        for (int nt = 0; nt < 4; ++nt)
#pragma unroll
            for (int rg = 0; rg < 4; ++rg) {
                float dd = (sc[0][nt][rg] - sc[1][nt][rg]) * 0.125f;
                bool msk = (mw[rg] >> (nt * 16 + l)) & 1ull;
                float p0 = msk ? 0.5f : __builtin_amdgcn_rcpf(1.f + __expf(-dd));
                int row = wv * 16 + qd * 4 + rg;
                *ldsp2(&Ps[0], row, g * 64 + nt * 16 + l) = f2bf(p0);
            }

        // PV: A from Ps slot g (own 16-row strip; b=1 frag = 1 - b=0 frag),
        // B from VTs (rows = d)
#pragma unroll
        for (int kc = 0; kc < 2; ++kc) {
            short8 af0 = *(const short8*)ldsp2(&Ps[0], wv * 16 + l, g * 64 + kc * 32 + qd * 8);
            short8 af1;
#pragma unroll
            for (int j = 0; j < 8; ++j) af1[j] = f2bf(1.f - bf2f(af0[j]));
#pragma unroll
            for (int nd = 0; nd < 4; ++nd) {
                short8 bf0 = *(const short8*)ldsp(&VTs[0][0], nd * 16 + l, kc * 32 + qd * 8);
                oacc[0][nd] = __builtin_amdgcn_mfma_f32_16x16x32_bf16(af0, bf0, oacc[0][nd], 0, 0, 0);
                short8 bf1 = *(const short8*)ldsp(&VTs[1][0], nd * 16 + l, kc * 32 + qd * 8);
                oacc[1][nd] = __builtin_amdgcn_mfma_f32_16x16x32_bf16(af1, bf1, oacc[1][nd], 0, 0, 0);
            }
        }
    }

    // epilogue: flush the last 4 ring slots (tiles tend-256 .. tend-64).
#pragma unroll
    for (int j = 0; j < 4; ++j)
        FLUSH(j, tend - 256 + j * 64);

    // partial O (C-layout: col=lane&15, row=quad*4+reg) -> ws
#pragma unroll
    for (int b = 0; b < 2; ++b)
#pragma unroll
        for (int nd = 0; nd < 4; ++nd)
#pragma unroll
            for (int rg = 0; rg < 4; ++rg) {
                int srow = s0 + wv * 16 + qd * 4 + rg;
                opart[(size_t)tz * OUTN +
                      ((size_t)(b * HDIM + h) * SDIM + srow) * DDIM + nd * 16 + l] =
                    oacc[b][nd][rg];
            }
}

// ---------------------------------------------------------------------------
// Sum the two t-half partials into out.
__global__ void combine(const float* __restrict__ opart, float* __restrict__ outg) {
    int gid = blockIdx.x * 256 + threadIdx.x;           // OUTN/4 threads
    f32x4 a = *(const f32x4*)(opart + (size_t)gid * 4);
    f32x4 b = *(const f32x4*)(opart + (size_t)OUTN + (size_t)gid * 4);
    *(f32x4*)(outg + (size_t)gid * 4) = a + b;
}

// ---------------------------------------------------------------------------
extern "C" void kernel_launch(void* const* d_in, const int* in_sizes, int n_in,
                              void* d_out, int out_size, void* d_ws, size_t ws_size,
                              hipStream_t stream) {
    (void)in_sizes; (void)n_in; (void)out_size; (void)ws_size;
    const float* qg  = (const float*)d_in[0];
    const float* kg  = (const float*)d_in[1];
    const float* vg  = (const float*)d_in[2];
    const int*   msk = (const int*)d_in[3];

    float* outg  = (float*)d_out;
    float* attng = outg + (size_t)OUTN;

    char* ws = (char*)d_ws;
    unsigned long long* bits = (unsigned long long*)ws;            // 2 MB
    short* qb = (short*)(ws + (size_t) 2 * 1024 * 1024);           // 4 MB
    short* kb = (short*)(ws + (size_t) 6 * 1024 * 1024);           // 4 MB
    short* vt = (short*)(ws + (size_t)10 * 1024 * 1024);           // 4 MB
    float* op = (float*)(ws + (size_t)14 * 1024 * 1024);           // 16.8 MB

    pack_mask  <<<dim3(SDIM * SDIM / 256), dim3(256), 0, stream>>>(msk, bits);
    cvt_bf16   <<<dim3(OUTN / (8 * 256)), dim3(256), 0, stream>>>(qg, qb);
    cvt_bf16   <<<dim3(OUTN / (8 * 256)), dim3(256), 0, stream>>>(kg, kb);
    transpose_v<<<dim3(OUTN / (8 * 256)), dim3(256), 0, stream>>>(vg, vt);
    attn_fused <<<dim3(SDIM / 64, HDIM, 2), dim3(256), 0, stream>>>(qb, kb, vt, bits, attng, op);
    combine    <<<dim3(OUTN / (4 * 256)), dim3(256), 0, stream>>>(op, outg);
}

// Round 13
// 178.783 us; speedup vs baseline: 1.2425x; 1.1061x over previous
//
#include <hip/hip_runtime.h>

// Problem: B=2, H=4, S=4096, D=64.  q,k,v fp32; mask int32.
// Outputs (fp32, concatenated): out [2,4,4096,64] then attn [2,4,4096,4096].
#define SDIM 4096
#define DDIM 64
#define HDIM 4
#define OUTN (2 * HDIM * SDIM * DDIM)   // 2,097,152 floats of `out` before `attn`

typedef short short8 __attribute__((ext_vector_type(8)));  // 8 x bf16 (4 VGPRs)
typedef short bh4    __attribute__((ext_vector_type(4)));  // 4 x bf16 (2 VGPRs)
typedef float f32x4  __attribute__((ext_vector_type(4)));

__device__ inline short f2bf(float f) {
    // round-to-nearest-even fp32 -> bf16
    unsigned u = __builtin_bit_cast(unsigned, f);
    u = (u + 0x7fffu + ((u >> 16) & 1u)) >> 16;
    return (short)u;
}
__device__ inline float bf2f(short s) {
    unsigned u = ((unsigned)(unsigned short)s) << 16;
    return __builtin_bit_cast(float, u);
}

// K/V LDS tiles are [64][64] shorts (128 B rows), XOR-swizzled: the 16-B
// chunk index (byte bits 4-6) is XORed with (row&7).  Keeps ds_read_b128 at
// the 8-cycle minimum (8 lanes / 4-bank group) with zero padding.
__device__ inline short* ldsp(short* base, int row, int colshort) {
    int byte = (row << 7) + (colshort << 1);
    byte ^= (row & 7) << 4;
    return (short*)((char*)base + byte);
}

// P accumulation tile is [64][256] shorts (512 B rows), same XOR scheme.
__device__ inline short* ldsp2(short* base, int row, int colshort) {
    int byte = (row << 9) + (colshort << 1);
    byte ^= (row & 7) << 4;
    return (short*)((char*)base + byte);
}

// async 16-B global -> LDS DMA (linear LDS dest; source is pre-swizzled)
__device__ inline void g2l16(const short* g, short* l) {
    __builtin_amdgcn_global_load_lds(
        (const __attribute__((address_space(1))) unsigned int*)g,
        (__attribute__((address_space(3))) unsigned int*)l, 16, 0, 0);
}

// ---------------------------------------------------------------------------
// Pre-pass 1: bit-pack mask (1,S,S) int32 -> 1 bit per element (2 MB in ws).
__global__ void pack_mask(const int* __restrict__ mask,
                          unsigned long long* __restrict__ bits) {
    int gid = blockIdx.x * 256 + threadIdx.x;
    int v = (mask[gid] != 0);
    unsigned long long bal = __ballot(v);
    if ((threadIdx.x & 63) == 0) bits[gid >> 6] = bal;
}

// ---------------------------------------------------------------------------
// Pre-pass 2: fp32 -> bf16 copy for Q AND K in one launch (block-uniform
// select).  8 elems/thread; first half of the grid handles q, second k.
__global__ void cvt_qk(const float* __restrict__ q, const float* __restrict__ k,
                       short* __restrict__ qb, short* __restrict__ kb) {
    int gid = blockIdx.x * 256 + threadIdx.x;
    const float* src = q;
    short* dst = qb;
    if (gid >= OUTN / 8) { src = k; dst = kb; gid -= OUTN / 8; }
    const float* p = src + (size_t)gid * 8;
    f32x4 a = *(const f32x4*)p;
    f32x4 b = *(const f32x4*)(p + 4);
    short8 o;
#pragma unroll
    for (int j = 0; j < 4; ++j) { o[j] = f2bf(a[j]); o[j + 4] = f2bf(b[j]); }
    *(short8*)(dst + (size_t)gid * 8) = o;
}

// ---------------------------------------------------------------------------
// Pre-pass 3: VT[b][h][d][t] = bf16(V[b][h][t][d])  (4 MB in ws).
// LDS-tiled: coalesced float4 reads of a 64x64 tile, bf16 into padded LDS
// (+2-short pad spreads the column reads across banks), coalesced short8
// writes.  Replaces the old scattered 4-B gather (16x read amplification).
__global__ void transpose_v(const float* __restrict__ v, short* __restrict__ vt) {
    __shared__ short T[64][66];             // +2 pad: col reads bank-spread
    const int bh = blockIdx.x >> 6;         // 0..7
    const int t0 = (blockIdx.x & 63) << 6;  // t-tile origin
    const int tid = threadIdx.x;
    const int tr = tid >> 2;                // 0..63: tile row (t)
    const int tc = tid & 3;                 // 0..3: 16-float column chunk

    const float* src = v + ((size_t)bh * SDIM + t0 + tr) * DDIM + tc * 16;
#pragma unroll
    for (int j = 0; j < 4; ++j) {
        f32x4 a = *(const f32x4*)(src + j * 4);
#pragma unroll
        for (int q = 0; q < 4; ++q) T[tr][tc * 16 + j * 4 + q] = f2bf(a[q]);
    }
    __syncthreads();

    const int d = tid >> 2;                 // 0..63: output row (d)
    short* dst = vt + ((size_t)bh * DDIM + d) * SDIM + t0 + tc * 16;
    short8 o0, o1;
#pragma unroll
    for (int k = 0; k < 8; ++k) { o0[k] = T[tc * 16 + k][d]; o1[k] = T[tc * 16 + 8 + k][d]; }
    *(short8*)dst = o0;
    *(short8*)(dst + 8) = o1;
}

// ---------------------------------------------------------------------------
// Fused kernel: block = (head h, 64 q-rows, BOTH batches, half the t range).
// BYTE-IDENTICAL to the R10 best (187.1 us):
// XCD-AWARE BLOCK SWIZZLE (T1, -21 us): XCD i runs the 64 s0-blocks of
// (h,tz)-combo i -> staged K/V reads hit the XCD's 4 MB L2.
// Per 64-wide t tile: S_b = Q_b K_b^T (MFMA) -> p0 = sigmoid((S0-S1)/8)
// (0.5 where masked) -> P0 into a 4-tile LDS accumulator (bf16; P1 = 1-P0
// recomputed in-register) -> O_b += P_b V_b (MFMA).  Every 4th tile: flush
// attn (1 KB contiguous fp32 per row) with NT stores (beats plain in both
// pre-/post-swizzle regimes; ring-flush reorder regressed -- R12).
// Partial O to ws; combined by `combine`.  LDS = 64 KB -> 2 blocks/CU.
__global__ __launch_bounds__(256, 2)
void attn_fused(const short* __restrict__ qg, const short* __restrict__ kg,
                const short* __restrict__ vtg,
                const unsigned long long* __restrict__ mbits,
                float* __restrict__ attng, float* __restrict__ opart) {
    __shared__ short Ks [2][64 * 64];       // K tile, rows = t (swizzled)
    __shared__ short VTs[2][64 * 64];       // V^T tile, rows = d (swizzled)
    __shared__ short Ps [64 * 256];         // P0 x 4 t-tiles, rows = m (swizzled)

    // XCD swizzle: orig -> swz (bijective 8x64 transpose over the 512 blocks)
    const int orig = blockIdx.x + (blockIdx.y << 6) + (blockIdx.z << 8);
    const int swz  = (orig & 7) * 64 + (orig >> 3);
    const int s0   = (swz & 63) << 6;       // q-row block
    const int cmb  = swz >> 6;              // (h,tz) combo 0..7
    const int h    = cmb & 3;
    const int tz   = cmb >> 2;              // t-half: [tz*2048, tz*2048+2048)

    const int tid = threadIdx.x;
    const int wv  = tid >> 6;               // wave 0..3, owns q-rows 16*wv..+15
    const int ln  = tid & 63;
    const int l   = ln & 15;
    const int qd  = ln >> 4;                // quad

    // Q A-fragments (A[m=lane&15][k=quad*8+j]), kept in registers.
    short8 qf[2][2];
#pragma unroll
    for (int b = 0; b < 2; ++b) {
        const size_t rb = ((size_t)(b * HDIM + h) * SDIM + (s0 + wv * 16 + l)) * DDIM;
#pragma unroll
        for (int kc = 0; kc < 2; ++kc)
            qf[b][kc] = *(const short8*)(qg + rb + kc * 32 + qd * 8);
    }

    f32x4 oacc[2][4];
#pragma unroll
    for (int b = 0; b < 2; ++b)
#pragma unroll
        for (int nd = 0; nd < 4; ++nd)
            oacc[b][nd] = (f32x4){0.f, 0.f, 0.f, 0.f};

    // staging geometry: lane ln covers dest row (p*32 + wv*8 + ln>>3),
    // chunk (ln&7); source chunk is inverse-swizzled so swizzled reads match.
    const int ln8 = ln >> 3;                 // dest row within 8-row group
    const int sc_ = (ln & 7) ^ ln8;          // pre-swizzled source 16-B chunk
    const int mrow0 = s0 + wv * 16 + qd * 4; // this quad's first C row

    const int tbeg = tz * (SDIM / 2);
    for (int t0 = tbeg; t0 < tbeg + SDIM / 2; t0 += 64) {
        __syncthreads();   // all waves done reading Ks/VTs of previous tile
#pragma unroll
        for (int b = 0; b < 2; ++b) {
            const short* kb = kg  + ((size_t)(b * HDIM + h) * SDIM + t0) * DDIM;
            const short* vb = vtg + ((size_t)(b * HDIM + h) * DDIM) * SDIM + t0;
#pragma unroll
            for (int p = 0; p < 2; ++p) {
                int rr = p * 32 + wv * 8 + ln8;
                g2l16(kb + (size_t)rr * DDIM + sc_ * 8, &Ks [b][p * 2048 + wv * 512]);
                g2l16(vb + (size_t)rr * SDIM + sc_ * 8, &VTs[b][p * 2048 + wv * 512]);
            }
        }
        // mask bits: one u64 per C row covers the 64 t of this tile
        // (independent of LDS -> issued under the staging DMA latency)
        unsigned long long mw[4];
#pragma unroll
        for (int rg = 0; rg < 4; ++rg)
            mw[rg] = mbits[(size_t)(mrow0 + rg) * (SDIM / 64) + (t0 >> 6)];
        __syncthreads();   // staged tiles visible (K/V are L2-hits now)

        const int g = (t0 >> 6) & 3;        // tile index within the 4-tile group

        // QK^T: B[k][n] = K[n][k] -> read K rows like A-frags
        f32x4 sc[2][4];
#pragma unroll
        for (int b = 0; b < 2; ++b)
#pragma unroll
            for (int nt = 0; nt < 4; ++nt) {
                f32x4 acc = (f32x4){0.f, 0.f, 0.f, 0.f};
#pragma unroll
                for (int kc = 0; kc < 2; ++kc) {
                    short8 bf = *(const short8*)ldsp(&Ks[b][0], nt * 16 + l, kc * 32 + qd * 8);
                    acc = __builtin_amdgcn_mfma_f32_16x16x32_bf16(qf[b][kc], bf, acc, 0, 0, 0);
                }
                sc[b][nt] = acc;
            }

        // batch-pair sigmoid; P0 -> Ps slot g (bf16, wave-local rows;
        // same-wave DS ordering covers the later same-wave reads)
#pragma unroll
        for (int nt = 0; nt < 4; ++nt)
#pragma unroll
            for (int rg = 0; rg < 4; ++rg) {
                float dd = (sc[0][nt][rg] - sc[1][nt][rg]) * 0.125f;
                bool msk = (mw[rg] >> (nt * 16 + l)) & 1ull;
                float p0 = msk ? 0.5f : __builtin_amdgcn_rcpf(1.f + __expf(-dd));
                int row = wv * 16 + qd * 4 + rg;
                *ldsp2(&Ps[0], row, g * 64 + nt * 16 + l) = f2bf(p0);
            }

        // PV: A from Ps slot g (own 16-row strip; b=1 frag = 1 - b=0 frag),
        // B from VTs (rows = d)
#pragma unroll
        for (int kc = 0; kc < 2; ++kc) {
            short8 af0 = *(const short8*)ldsp2(&Ps[0], wv * 16 + l, g * 64 + kc * 32 + qd * 8);
            short8 af1;
#pragma unroll
            for (int j = 0; j < 8; ++j) af1[j] = f2bf(1.f - bf2f(af0[j]));
#pragma unroll
            for (int nd = 0; nd < 4; ++nd) {
                short8 bf0 = *(const short8*)ldsp(&VTs[0][0], nd * 16 + l, kc * 32 + qd * 8);
                oacc[0][nd] = __builtin_amdgcn_mfma_f32_16x16x32_bf16(af0, bf0, oacc[0][nd], 0, 0, 0);
                short8 bf1 = *(const short8*)ldsp(&VTs[1][0], nd * 16 + l, kc * 32 + qd * 8);
                oacc[1][nd] = __builtin_amdgcn_mfma_f32_16x16x32_bf16(af1, bf1, oacc[1][nd], 0, 0, 0);
            }
        }

        // FLUSH every 4th tile: per 4-row group, 4 consecutive store
        // instructions cover 1 KB CONTIGUOUS fp32 per row (t-inner order).
        if (g == 3) {
            int rr2 = ln >> 4;               // row within 4-row group
            int c2  = ln & 15;               // 16-B chunk within a 256-B segment
            int tg0 = t0 & ~255;             // first t of this 4-tile group
#pragma unroll
            for (int b = 0; b < 2; ++b) {
                size_t ab = ((size_t)(b * HDIM + h) * SDIM + s0) * (size_t)SDIM + tg0;
#pragma unroll
                for (int sub = 0; sub < 4; ++sub) {
                    int row = wv * 16 + sub * 4 + rr2;
                    float* dst = attng + ab + (size_t)row * SDIM;
#pragma unroll
                    for (int tch = 0; tch < 4; ++tch) {
                        bh4 pv = *(const bh4*)ldsp2(&Ps[0], row, tch * 64 + c2 * 4);
                        f32x4 o;
#pragma unroll
                        for (int j = 0; j < 4; ++j) {
                            float v = bf2f(pv[j]);
                            o[j] = b ? 1.f - v : v;
                        }
                        __builtin_nontemporal_store(
                            o, (f32x4*)(dst + tch * 64 + c2 * 4));
                    }
                }
            }
        }
    }

    // epilogue: partial O (C-layout: col=lane&15, row=quad*4+reg) -> ws
#pragma unroll
    for (int b = 0; b < 2; ++b)
#pragma unroll
        for (int nd = 0; nd < 4; ++nd)
#pragma unroll
            for (int rg = 0; rg < 4; ++rg) {
                int srow = s0 + wv * 16 + qd * 4 + rg;
                opart[(size_t)tz * OUTN +
                      ((size_t)(b * HDIM + h) * SDIM + srow) * DDIM + nd * 16 + l] =
                    oacc[b][nd][rg];
            }
}

// ---------------------------------------------------------------------------
// Sum the two t-half partials into out.
__global__ void combine(const float* __restrict__ opart, float* __restrict__ outg) {
    int gid = blockIdx.x * 256 + threadIdx.x;           // OUTN/4 threads
    f32x4 a = *(const f32x4*)(opart + (size_t)gid * 4);
    f32x4 b = *(const f32x4*)(opart + (size_t)OUTN + (size_t)gid * 4);
    *(f32x4*)(outg + (size_t)gid * 4) = a + b;
}

// ---------------------------------------------------------------------------
extern "C" void kernel_launch(void* const* d_in, const int* in_sizes, int n_in,
                              void* d_out, int out_size, void* d_ws, size_t ws_size,
                              hipStream_t stream) {
    (void)in_sizes; (void)n_in; (void)out_size; (void)ws_size;
    const float* qg  = (const float*)d_in[0];
    const float* kg  = (const float*)d_in[1];
    const float* vg  = (const float*)d_in[2];
    const int*   msk = (const int*)d_in[3];

    float* outg  = (float*)d_out;
    float* attng = outg + (size_t)OUTN;

    char* ws = (char*)d_ws;
    unsigned long long* bits = (unsigned long long*)ws;            // 2 MB
    short* qb = (short*)(ws + (size_t) 2 * 1024 * 1024);           // 4 MB
    short* kb = (short*)(ws + (size_t) 6 * 1024 * 1024);           // 4 MB
    short* vt = (short*)(ws + (size_t)10 * 1024 * 1024);           // 4 MB
    float* op = (float*)(ws + (size_t)14 * 1024 * 1024);           // 16.8 MB

    pack_mask  <<<dim3(SDIM * SDIM / 256), dim3(256), 0, stream>>>(msk, bits);
    cvt_qk     <<<dim3(2 * OUTN / (8 * 256)), dim3(256), 0, stream>>>(qg, kg, qb, kb);
    transpose_v<<<dim3(8 * (SDIM / 64)), dim3(256), 0, stream>>>(vg, vt);
    attn_fused <<<dim3(SDIM / 64, HDIM, 2), dim3(256), 0, stream>>>(qb, kb, vt, bits, attng, op);
    combine    <<<dim3(OUTN / (4 * 256)), dim3(256), 0, stream>>>(op, outg);
}